// Round 1
// baseline (2087.234 us; speedup 1.0000x reference)
//
#include <hip/hip_runtime.h>

#define NR 8

// ---------------------------------------------------------------------------
// Accumulator layout (inside d_out, so no workspace-size assumption):
//   ZM[a][r]     lives at out[a*72 + r]            (== h_s0 output, kept)
//   FM[a][s][i]  lives at out[A*72 + a*192 + s*3+i] (overwritten by h_p later)
// ---------------------------------------------------------------------------

__global__ void zero_acc_kernel(float* __restrict__ out, int n_atoms) {
    int tid = blockIdx.x * blockDim.x + threadIdx.x;   // one float4 per thread
    if (tid >= n_atoms * 8) return;
    int atom = tid >> 3;
    int q    = tid & 7;
    float4 z = make_float4(0.f, 0.f, 0.f, 0.f);
    if (q < 2) {
        // ZM: 8 floats = 2 float4 at out + atom*72  (288B, 16B aligned)
        reinterpret_cast<float4*>(out + (size_t)atom * 72)[q] = z;
    } else {
        // FM: 24 floats = 6 float4 at hp row start (768B rows, 16B aligned)
        reinterpret_cast<float4*>(out + (size_t)n_atoms * 72 + (size_t)atom * 192)[q - 2] = z;
    }
}

__global__ void scatter_kernel(const float* __restrict__ dn,
                               const float* __restrict__ hs,
                               const float* __restrict__ basis,
                               const int*   __restrict__ idx,
                               float* __restrict__ out,
                               int n_edges, int n_atoms) {
    int e = blockIdx.x * blockDim.x + threadIdx.x;
    if (e >= n_edges) return;

    const float4* hsp = reinterpret_cast<const float4*>(hs + (size_t)e * NR);
    const float4* bp  = reinterpret_cast<const float4*>(basis + (size_t)e * NR);
    float4 h0 = hsp[0], h1 = hsp[1];
    float4 b0 = bp[0],  b1 = bp[1];

    float d0 = dn[(size_t)e * 3 + 0];
    float d1 = dn[(size_t)e * 3 + 1];
    float d2 = dn[(size_t)e * 3 + 2];

    float zm[NR];
    zm[0] = h0.x * b0.x; zm[1] = h0.y * b0.y; zm[2] = h0.z * b0.z; zm[3] = h0.w * b0.w;
    zm[4] = h1.x * b1.x; zm[5] = h1.y * b1.y; zm[6] = h1.z * b1.z; zm[7] = h1.w * b1.w;

    int a = idx[e];
    float* zp = out + (size_t)a * 72;
    float* fp = out + (size_t)n_atoms * 72 + (size_t)a * 192;

#pragma unroll
    for (int r = 0; r < NR; ++r) {
        atomicAdd(zp + r, zm[r]);
    }
#pragma unroll
    for (int r = 0; r < NR; ++r) {
        atomicAdd(fp + r * 3 + 0, zm[r] * d0);
        atomicAdd(fp + r * 3 + 1, zm[r] * d1);
        atomicAdd(fp + r * 3 + 2, zm[r] * d2);
    }
}

// One wave (64 lanes) per atom. lane = r*8+s.
__global__ void contract_kernel(float* __restrict__ out, int n_atoms) {
    int atom = blockIdx.x * 4 + (threadIdx.x >> 6);
    if (atom >= n_atoms) return;
    int lane = threadIdx.x & 63;

    float* zrow = out + (size_t)atom * 72;
    float* prow = out + (size_t)n_atoms * 72 + (size_t)atom * 192;

    // lanes 0..7 hold ZM[0..7]; lanes 8..31 hold FM[0..23] (s-major, 3 per s)
    float x = 0.f;
    if (lane < 8)       x = zrow[lane];
    else if (lane < 32) x = prow[lane - 8];

    int r = lane >> 3;
    int s = lane & 7;

    float zr  = __shfl(x, r);
    float fr0 = __shfl(x, 8 + r * 3 + 0);
    float fr1 = __shfl(x, 8 + r * 3 + 1);
    float fr2 = __shfl(x, 8 + r * 3 + 2);
    float fs0 = __shfl(x, 8 + s * 3 + 0);
    float fs1 = __shfl(x, 8 + s * 3 + 1);
    float fs2 = __shfl(x, 8 + s * 3 + 2);

    // h_s1[r,s] = sum_i FM[r][i]*FM[s][i]
    float hs1 = fr0 * fs0 + fr1 * fs1 + fr2 * fs2;

    // h_s_out row: [ZM(8) | hs1(64)] — ZM already correct in memory.
    zrow[8 + lane] = hs1;

    // h_p[a,i,r,s] = ZM[r] * FM[s][i]; row layout [3][64], inner = r*8+s = lane
    prow[lane]       = zr * fs0;   // overwrites FM storage — after all loads (shfl dep)
    prow[64 + lane]  = zr * fs1;
    prow[128 + lane] = zr * fs2;
}

extern "C" void kernel_launch(void* const* d_in, const int* in_sizes, int n_in,
                              void* d_out, int out_size, void* d_ws, size_t ws_size,
                              hipStream_t stream) {
    const float* dn    = (const float*)d_in[0];
    const float* hs    = (const float*)d_in[1];
    const float* basis = (const float*)d_in[2];
    const int*   idx   = (const int*)d_in[3];
    float* out = (float*)d_out;

    int n_edges = in_sizes[0] / 3;
    int n_atoms = in_sizes[1] / NR;

    {
        int total = n_atoms * 8;
        int blk = 256;
        zero_acc_kernel<<<(total + blk - 1) / blk, blk, 0, stream>>>(out, n_atoms);
    }
    {
        int blk = 256;
        scatter_kernel<<<(n_edges + blk - 1) / blk, blk, 0, stream>>>(
            dn, hs, basis, idx, out, n_edges, n_atoms);
    }
    {
        int blk = 256;  // 4 waves = 4 atoms per block
        int blocks = (n_atoms + 3) / 4;
        contract_kernel<<<blocks, blk, 0, stream>>>(out, n_atoms);
    }
}

// Round 3
// 526.901 us; speedup vs baseline: 3.9613x; 3.9613x over previous
//
#include <hip/hip_runtime.h>

#define NR 8
#define SCAN_BS 256
#define SCAN_E  1024   // elements scanned per block (4 per thread)

// ===========================================================================
// CSR path (uses d_ws):
//   ws layout (bytes):
//     count   : n_atoms * 4          @ 0
//     offsets : (n_atoms+1) * 4      @ OFF_OFFS
//     rank    : n_edges * 4          @ OFF_RANK
//     partial : NB1 * 4              @ OFF_PART
//     ordered : n_edges * 32 * 4     @ OFF_ORD  (16MB-aligned region)
// Fallback path (ws too small): round-1 atomic-accumulate version.
// ===========================================================================

// --------------------------- CSR kernels -----------------------------------

__global__ void count_kernel(const int* __restrict__ idx,
                             int* __restrict__ cnt,
                             int* __restrict__ rank, int n_edges) {
    int e = blockIdx.x * blockDim.x + threadIdx.x;
    if (e < n_edges) rank[e] = atomicAdd(&cnt[idx[e]], 1);
}

// per-block inclusive scan -> exclusive per element; block totals to partial[]
__global__ void scan1_kernel(const int* __restrict__ cnt,
                             int* __restrict__ scanned,
                             int* __restrict__ partial, int n) {
    __shared__ int sh[SCAN_BS];
    int b = blockIdx.x, t = threadIdx.x;
    int base = b * SCAN_E + t * 4;
    int c0 = (base + 0 < n) ? cnt[base + 0] : 0;
    int c1 = (base + 1 < n) ? cnt[base + 1] : 0;
    int c2 = (base + 2 < n) ? cnt[base + 2] : 0;
    int c3 = (base + 3 < n) ? cnt[base + 3] : 0;
    int s = c0 + c1 + c2 + c3;
    sh[t] = s;
    __syncthreads();
    for (int off = 1; off < SCAN_BS; off <<= 1) {
        int v = (t >= off) ? sh[t - off] : 0;
        __syncthreads();
        sh[t] += v;
        __syncthreads();
    }
    int incl = sh[t];
    int excl = incl - s;
    if (base + 0 < n) scanned[base + 0] = excl;
    if (base + 1 < n) scanned[base + 1] = excl + c0;
    if (base + 2 < n) scanned[base + 2] = excl + c0 + c1;
    if (base + 3 < n) scanned[base + 3] = excl + c0 + c1 + c2;
    if (t == SCAN_BS - 1) partial[b] = incl;
}

__global__ void scan2_kernel(int* __restrict__ partial, int nb) {
    __shared__ int sh[1024];
    int t = threadIdx.x;
    int v = (t < nb) ? partial[t] : 0;
    sh[t] = v;
    __syncthreads();
    for (int off = 1; off < 1024; off <<= 1) {
        int u = (t >= off) ? sh[t - off] : 0;
        __syncthreads();
        sh[t] += u;
        __syncthreads();
    }
    if (t < nb) partial[t] = sh[t] - v;   // exclusive
}

__global__ void scan3_kernel(int* __restrict__ offsets,
                             const int* __restrict__ partial,
                             int n, int total) {
    int i = blockIdx.x * blockDim.x + threadIdx.x;
    if (i < n) offsets[i] += partial[i >> 10];   // SCAN_E == 1024
    if (i == 0) offsets[n] = total;
}

__global__ void __launch_bounds__(256) scatter_csr_kernel(
        const float* __restrict__ dn,
        const float* __restrict__ hs,
        const float* __restrict__ basis,
        const int*   __restrict__ idx,
        const int*   __restrict__ offsets,
        const int*   __restrict__ rank,
        float* __restrict__ ordered,
        int n_edges) {
    int e = blockIdx.x * blockDim.x + threadIdx.x;
    if (e >= n_edges) return;

    const float4* hsp = reinterpret_cast<const float4*>(hs + (size_t)e * NR);
    const float4* bp  = reinterpret_cast<const float4*>(basis + (size_t)e * NR);
    float4 h0 = hsp[0], h1 = hsp[1];
    float4 b0 = bp[0],  b1 = bp[1];

    float d0 = dn[(size_t)e * 3 + 0];
    float d1 = dn[(size_t)e * 3 + 1];
    float d2 = dn[(size_t)e * 3 + 2];

    float v[32];
    v[0] = h0.x * b0.x; v[1] = h0.y * b0.y; v[2] = h0.z * b0.z; v[3] = h0.w * b0.w;
    v[4] = h1.x * b1.x; v[5] = h1.y * b1.y; v[6] = h1.z * b1.z; v[7] = h1.w * b1.w;
#pragma unroll
    for (int s = 0; s < NR; ++s) {
        v[8 + s * 3 + 0] = v[s] * d0;
        v[8 + s * 3 + 1] = v[s] * d1;
        v[8 + s * 3 + 2] = v[s] * d2;
    }

    int slot = offsets[idx[e]] + rank[e];
    float4* dst = reinterpret_cast<float4*>(ordered + (size_t)slot * 32);
#pragma unroll
    for (int k = 0; k < 8; ++k) {
        dst[k] = make_float4(v[4 * k], v[4 * k + 1], v[4 * k + 2], v[4 * k + 3]);
    }
}

// One wave per atom: gather segment, contract, write outputs.
__global__ void contract_csr_kernel(const float* __restrict__ ordered,
                                    const int* __restrict__ offsets,
                                    float* __restrict__ out, int n_atoms) {
    int atom = blockIdx.x * 4 + (threadIdx.x >> 6);
    if (atom >= n_atoms) return;
    int lane = threadIdx.x & 63;

    int start = offsets[atom];
    int end   = offsets[atom + 1];

    float x = 0.f;
    if (lane < 32) {
        for (int b = start; b < end; ++b)
            x += ordered[(size_t)b * 32 + lane];
    }

    int r = lane >> 3;
    int s = lane & 7;

    float zr  = __shfl(x, r);
    float fr0 = __shfl(x, 8 + r * 3 + 0);
    float fr1 = __shfl(x, 8 + r * 3 + 1);
    float fr2 = __shfl(x, 8 + r * 3 + 2);
    float fs0 = __shfl(x, 8 + s * 3 + 0);
    float fs1 = __shfl(x, 8 + s * 3 + 1);
    float fs2 = __shfl(x, 8 + s * 3 + 2);

    float hs1 = fr0 * fs0 + fr1 * fs1 + fr2 * fs2;

    float* zrow = out + (size_t)atom * 72;
    float* prow = out + (size_t)n_atoms * 72 + (size_t)atom * 192;

    if (lane < 8) zrow[lane] = x;       // ZM
    zrow[8 + lane] = hs1;               // h_s1

    prow[lane]       = zr * fs0;        // h_p[i=0]
    prow[64 + lane]  = zr * fs1;        // h_p[i=1]
    prow[128 + lane] = zr * fs2;        // h_p[i=2]
}

// --------------------- fallback (round-1 atomic) kernels --------------------

__global__ void zero_acc_kernel(float* __restrict__ out, int n_atoms) {
    int tid = blockIdx.x * blockDim.x + threadIdx.x;
    if (tid >= n_atoms * 8) return;
    int atom = tid >> 3;
    int q    = tid & 7;
    float4 z = make_float4(0.f, 0.f, 0.f, 0.f);
    if (q < 2) {
        reinterpret_cast<float4*>(out + (size_t)atom * 72)[q] = z;
    } else {
        reinterpret_cast<float4*>(out + (size_t)n_atoms * 72 + (size_t)atom * 192)[q - 2] = z;
    }
}

__global__ void scatter_atomic_kernel(const float* __restrict__ dn,
                                      const float* __restrict__ hs,
                                      const float* __restrict__ basis,
                                      const int*   __restrict__ idx,
                                      float* __restrict__ out,
                                      int n_edges, int n_atoms) {
    int e = blockIdx.x * blockDim.x + threadIdx.x;
    if (e >= n_edges) return;

    const float4* hsp = reinterpret_cast<const float4*>(hs + (size_t)e * NR);
    const float4* bp  = reinterpret_cast<const float4*>(basis + (size_t)e * NR);
    float4 h0 = hsp[0], h1 = hsp[1];
    float4 b0 = bp[0],  b1 = bp[1];

    float d0 = dn[(size_t)e * 3 + 0];
    float d1 = dn[(size_t)e * 3 + 1];
    float d2 = dn[(size_t)e * 3 + 2];

    float zm[NR];
    zm[0] = h0.x * b0.x; zm[1] = h0.y * b0.y; zm[2] = h0.z * b0.z; zm[3] = h0.w * b0.w;
    zm[4] = h1.x * b1.x; zm[5] = h1.y * b1.y; zm[6] = h1.z * b1.z; zm[7] = h1.w * b1.w;

    int a = idx[e];
    float* zp = out + (size_t)a * 72;
    float* fp = out + (size_t)n_atoms * 72 + (size_t)a * 192;

#pragma unroll
    for (int r = 0; r < NR; ++r) atomicAdd(zp + r, zm[r]);
#pragma unroll
    for (int r = 0; r < NR; ++r) {
        atomicAdd(fp + r * 3 + 0, zm[r] * d0);
        atomicAdd(fp + r * 3 + 1, zm[r] * d1);
        atomicAdd(fp + r * 3 + 2, zm[r] * d2);
    }
}

__global__ void contract_inplace_kernel(float* __restrict__ out, int n_atoms) {
    int atom = blockIdx.x * 4 + (threadIdx.x >> 6);
    if (atom >= n_atoms) return;
    int lane = threadIdx.x & 63;

    float* zrow = out + (size_t)atom * 72;
    float* prow = out + (size_t)n_atoms * 72 + (size_t)atom * 192;

    float x = 0.f;
    if (lane < 8)       x = zrow[lane];
    else if (lane < 32) x = prow[lane - 8];

    int r = lane >> 3;
    int s = lane & 7;

    float zr  = __shfl(x, r);
    float fr0 = __shfl(x, 8 + r * 3 + 0);
    float fr1 = __shfl(x, 8 + r * 3 + 1);
    float fr2 = __shfl(x, 8 + r * 3 + 2);
    float fs0 = __shfl(x, 8 + s * 3 + 0);
    float fs1 = __shfl(x, 8 + s * 3 + 1);
    float fs2 = __shfl(x, 8 + s * 3 + 2);

    float hs1 = fr0 * fs0 + fr1 * fs1 + fr2 * fs2;

    zrow[8 + lane] = hs1;
    prow[lane]       = zr * fs0;
    prow[64 + lane]  = zr * fs1;
    prow[128 + lane] = zr * fs2;
}

// ---------------------------------------------------------------------------

extern "C" void kernel_launch(void* const* d_in, const int* in_sizes, int n_in,
                              void* d_out, int out_size, void* d_ws, size_t ws_size,
                              hipStream_t stream) {
    const float* dn    = (const float*)d_in[0];
    const float* hs    = (const float*)d_in[1];
    const float* basis = (const float*)d_in[2];
    const int*   idx   = (const int*)d_in[3];
    float* out = (float*)d_out;

    int n_edges = in_sizes[0] / 3;
    int n_atoms = in_sizes[1] / NR;
    int nb1 = (n_atoms + SCAN_E - 1) / SCAN_E;

    // ws layout
    size_t off_offs = (size_t)n_atoms * 4;
    size_t off_rank = off_offs + (size_t)(n_atoms + 1) * 4;
    size_t off_part = off_rank + (size_t)n_edges * 4;
    size_t off_ord  = (off_part + (size_t)nb1 * 4 + 255) & ~(size_t)255;
    size_t ws_needed = off_ord + (size_t)n_edges * 32 * 4;

    if (ws_size >= ws_needed && nb1 <= 1024) {
        char* ws = (char*)d_ws;
        int* cnt     = (int*)ws;
        int* offsets = (int*)(ws + off_offs);
        int* rank    = (int*)(ws + off_rank);
        int* partial = (int*)(ws + off_part);
        float* ordered = (float*)(ws + off_ord);

        hipMemsetAsync(cnt, 0, (size_t)n_atoms * 4, stream);

        int blk = 256;
        count_kernel<<<(n_edges + blk - 1) / blk, blk, 0, stream>>>(
            idx, cnt, rank, n_edges);

        scan1_kernel<<<nb1, SCAN_BS, 0, stream>>>(cnt, offsets, partial, n_atoms);
        scan2_kernel<<<1, 1024, 0, stream>>>(partial, nb1);
        scan3_kernel<<<(n_atoms + blk - 1) / blk, blk, 0, stream>>>(
            offsets, partial, n_atoms, n_edges);

        scatter_csr_kernel<<<(n_edges + blk - 1) / blk, blk, 0, stream>>>(
            dn, hs, basis, idx, offsets, rank, ordered, n_edges);

        contract_csr_kernel<<<(n_atoms + 3) / 4, 256, 0, stream>>>(
            ordered, offsets, out, n_atoms);
    } else {
        // fallback: round-1 atomic path
        int blk = 256;
        int total = n_atoms * 8;
        zero_acc_kernel<<<(total + blk - 1) / blk, blk, 0, stream>>>(out, n_atoms);
        scatter_atomic_kernel<<<(n_edges + blk - 1) / blk, blk, 0, stream>>>(
            dn, hs, basis, idx, out, n_edges, n_atoms);
        contract_inplace_kernel<<<(n_atoms + 3) / 4, 256, 0, stream>>>(out, n_atoms);
    }
}